// Round 7
// baseline (234.092 us; speedup 1.0000x reference)
//
#include <hip/hip_runtime.h>

// Depth-4 path signature, D=6 — SINGLE fused launch.
// Phase A: 1000 blocks x 256 threads; wave w computes chunk 4b+w via the
//   36-lane Chen recursion on LDS-precomputed increment rows (zero-padded:
//   v=0 is an exact no-op step, so the loop is branch-free with fixed CL).
// Phase B: block combines its 4 wave-states in LDS (216-lane layout).
// Phase C: last-arriver election (threadfence+atomicAdd, rocPRIM pattern):
//   group of 32 blocks -> 31 products; then last of 32 group-combiners ->
//   31 products -> d_out. Zero states are exact Chen identities.
// All per-lane state is NAMED SCALARS (R2-R4: arrays land in scratch).
//
// Internal state layout (floats): L4 [0,1296) L3 [1296,1512) L2 [1512,1548)
// L1 [1548,1554). Output uses reference layout L1|L2|L3|L4.
#define SIGSZ 1554
#define PSTRIDE 1600
#define OFF4 0
#define OFF3 1296
#define OFF2 1512
#define OFF1 1548
#define SSTRIDE 1560      // LDS state stride
#define MAXCL 32
#define NBMAX 2048
#define NGMAX 64
#define GSZ 32

#define REP6(M) M(0) M(1) M(2) M(3) M(4) M(5)
#define REP6B(M, k) M(k, 0) M(k, 1) M(k, 2) M(k, 3) M(k, 4) M(k, 5)
#define REP36(M) \
  REP6B(M, 0) REP6B(M, 1) REP6B(M, 2) REP6B(M, 3) REP6B(M, 4) REP6B(M, 5)

__device__ __forceinline__ float sel6(int idx, float a0, float a1, float a2,
                                      float a3, float a4, float a5) {
  float r = a0;
  r = (idx == 1) ? a1 : r;
  r = (idx == 2) ? a2 : r;
  r = (idx == 3) ? a3 : r;
  r = (idx == 4) ? a4 : r;
  r = (idx == 5) ? a5 : r;
  return r;
}

// ---- combine working set: 32 named scalars per prefetch slot ----
#define DECLSET(S)                                                  \
  float S##b4_0, S##b4_1, S##b4_2, S##b4_3, S##b4_4, S##b4_5;       \
  float S##b3r_0, S##b3r_1, S##b3r_2, S##b3r_3, S##b3r_4, S##b3r_5; \
  float S##b2r_0, S##b2r_1, S##b2r_2, S##b2r_3, S##b2r_4, S##b2r_5; \
  float S##b1_0, S##b1_1, S##b1_2, S##b1_3, S##b1_4, S##b1_5;       \
  float S##b2ij, S##b2jk, S##b3ijk, S##b1k, S##b1j, S##b1i;

#define LOADSET(S, bp) {                                            \
  const float2* q4 = (const float2*)((bp) + oB4);                   \
  float2 u0 = q4[0], u1 = q4[1], u2 = q4[2];                        \
  S##b4_0 = u0.x; S##b4_1 = u0.y; S##b4_2 = u1.x;                   \
  S##b4_3 = u1.y; S##b4_4 = u2.x; S##b4_5 = u2.y;                   \
  const float2* q3 = (const float2*)((bp) + oB3r);                  \
  float2 w0 = q3[0], w1 = q3[1], w2 = q3[2];                        \
  S##b3r_0 = w0.x; S##b3r_1 = w0.y; S##b3r_2 = w1.x;                \
  S##b3r_3 = w1.y; S##b3r_4 = w2.x; S##b3r_5 = w2.y;                \
  const float2* q2 = (const float2*)((bp) + oB2r);                  \
  float2 y0 = q2[0], y1 = q2[1], y2 = q2[2];                        \
  S##b2r_0 = y0.x; S##b2r_1 = y0.y; S##b2r_2 = y1.x;                \
  S##b2r_3 = y1.y; S##b2r_4 = y2.x; S##b2r_5 = y2.y;                \
  const float2* q1 = (const float2*)((bp) + OFF1);                  \
  float2 z0 = q1[0], z1 = q1[1], z2 = q1[2];                        \
  S##b1_0 = z0.x; S##b1_1 = z0.y; S##b1_2 = z1.x;                   \
  S##b1_3 = z1.y; S##b1_4 = z2.x; S##b1_5 = z2.y;                   \
  S##b2ij = (bp)[oB2ij]; S##b2jk = (bp)[oB2jk];                     \
  S##b3ijk = (bp)[oB3ijk];                                          \
  S##b1k = (bp)[oB1k]; S##b1j = (bp)[oB1j]; S##b1i = (bp)[oB1i];    \
}

// C = A (x) B, old-A on RHS; updates a-regs in place.
#define PROD(S) {                                                   \
  a4_0 = fmaf(a3, S##b1_0, fmaf(a2, S##b2r_0,                       \
         fmaf(a1i, S##b3r_0, a4_0 + S##b4_0)));                     \
  a4_1 = fmaf(a3, S##b1_1, fmaf(a2, S##b2r_1,                       \
         fmaf(a1i, S##b3r_1, a4_1 + S##b4_1)));                     \
  a4_2 = fmaf(a3, S##b1_2, fmaf(a2, S##b2r_2,                       \
         fmaf(a1i, S##b3r_2, a4_2 + S##b4_2)));                     \
  a4_3 = fmaf(a3, S##b1_3, fmaf(a2, S##b2r_3,                       \
         fmaf(a1i, S##b3r_3, a4_3 + S##b4_3)));                     \
  a4_4 = fmaf(a3, S##b1_4, fmaf(a2, S##b2r_4,                       \
         fmaf(a1i, S##b3r_4, a4_4 + S##b4_4)));                     \
  a4_5 = fmaf(a3, S##b1_5, fmaf(a2, S##b2r_5,                       \
         fmaf(a1i, S##b3r_5, a4_5 + S##b4_5)));                     \
  a3 = fmaf(a2, S##b1k, fmaf(a1i, S##b2jk, a3 + S##b3ijk));         \
  a2 = fmaf(a1i, S##b1j, a2 + S##b2ij);                             \
  a1i += S##b1i;                                                    \
  a1_0 += S##b1_0; a1_1 += S##b1_1; a1_2 += S##b1_2;                \
  a1_3 += S##b1_3; a1_4 += S##b1_4; a1_5 += S##b1_5;                \
}

#define INITA(bp) {                                                 \
  const float2* q4 = (const float2*)((bp) + oB4);                   \
  float2 u0 = q4[0], u1 = q4[1], u2 = q4[2];                        \
  a4_0 = u0.x; a4_1 = u0.y; a4_2 = u1.x;                            \
  a4_3 = u1.y; a4_4 = u2.x; a4_5 = u2.y;                            \
  a3 = (bp)[oB3ijk]; a2 = (bp)[oB2ij];                              \
  const float2* q1 = (const float2*)((bp) + OFF1);                  \
  float2 z0 = q1[0], z1 = q1[1], z2 = q1[2];                        \
  a1_0 = z0.x; a1_1 = z0.y; a1_2 = z1.x;                            \
  a1_3 = z1.y; a1_4 = z2.x; a1_5 = z2.y;                            \
  a1i = (bp)[oB1i];                                                 \
}

// left-to-right combine of states base[1..n-1] into a-regs (A=base[0] loaded
// by INITA), 2-deep ping-pong prefetch, clamped tail loads.
#define GCLAMP(sx, n) (((sx) < (n)) ? (sx) : ((n) - 1))
#define GLOOP(base, n) {                                            \
  int s_ = 1;                                                       \
  LOADSET(A, (base) + (size_t)GCLAMP(1, (n)) * PSTRIDE)             \
  LOADSET(B, (base) + (size_t)GCLAMP(2, (n)) * PSTRIDE)             \
  while (s_ + 1 < (n)) {                                            \
    PROD(A)                                                         \
    LOADSET(A, (base) + (size_t)GCLAMP(s_ + 2, (n)) * PSTRIDE)      \
    PROD(B)                                                         \
    LOADSET(B, (base) + (size_t)GCLAMP(s_ + 3, (n)) * PSTRIDE)      \
    s_ += 2;                                                        \
  }                                                                 \
  if (s_ < (n)) { PROD(A) }                                         \
}

// write a-regs as an internal-layout state (216-lane)
#define STORE_STATE(dst) {                                          \
  if (act2) {                                                       \
    float2* o2 = (float2*)((dst) + oB4);                            \
    float2 wv_;                                                     \
    wv_.x = a4_0; wv_.y = a4_1; o2[0] = wv_;                        \
    wv_.x = a4_2; wv_.y = a4_3; o2[1] = wv_;                        \
    wv_.x = a4_4; wv_.y = a4_5; o2[2] = wv_;                        \
    (dst)[oB3ijk] = a3;                                             \
    if (k2 == 0) (dst)[oB2ij] = a2;                                 \
  }                                                                 \
  if (tid < 6) (dst)[OFF1 + tid] = sel6(tid, a1_0, a1_1, a1_2,      \
                                        a1_3, a1_4, a1_5);          \
}

__global__ __launch_bounds__(256) void sig_fused(
    const float* __restrict__ x, float* __restrict__ ws1,
    float* __restrict__ ws2, int* __restrict__ ctr,
    float* __restrict__ out, int n_inc, int CL, int NB, int NG1) {
  __shared__ __align__(16) float xls[(4 * MAXCL + 1) * 6];
  __shared__ __align__(16) float vls[4 * MAXCL * 6];
  __shared__ __align__(16) float Sb[4 * SSTRIDE];
  __shared__ int flag;

  const int b = blockIdx.x;
  const int tid = threadIdx.x;
  const int w = tid >> 6;
  const int lane = tid & 63;

  // ---- stage x rows, then zero-padded increment rows, into LDS ----
  const int t0b = b * 4 * CL;
  const int xtot = (4 * CL + 1) * 6;
  const int xlim = (n_inc + 1) * 6 - t0b * 6;   // valid staged floats
  for (int idx = tid; idx < xtot; idx += 256)
    xls[idx] = (idx < xlim) ? x[(size_t)t0b * 6 + idx] : 0.f;
  __syncthreads();
  const int remi = n_inc - t0b;
  const int vlim = (remi > 0) ? remi * 6 : 0;
  const int vtot = 4 * CL * 6;
  for (int idx = tid; idx < vtot; idx += 256)
    vls[idx] = (idx < vlim) ? (xls[idx + 6] - xls[idx]) : 0.f;
  __syncthreads();

  // ---- Phase A: per-wave 36-lane Chen recursion over CL increments ----
  const int pc = (lane < 36) ? lane : 35;
  const int i_ = pc / 6, j_ = pc % 6;

#define DECL_S4(k, l) float s4_##k##_##l = 0.f;
  REP36(DECL_S4)
#undef DECL_S4
#define DECL_S3(k) float s3_##k = 0.f;
  REP6(DECL_S3)
#undef DECL_S3
  float s1i = 0.f, s2 = 0.f;

  const float* vp = vls + w * CL * 6;
  float va0, va1, va2, va3, va4, va5, vb0, vb1, vb2, vb3, vb4, vb5;
  {
    const float2* q0 = (const float2*)(vp);
    float2 a0 = q0[0], b0 = q0[1], d0 = q0[2];
    va0 = a0.x; va1 = a0.y; va2 = b0.x; va3 = b0.y; va4 = d0.x; va5 = d0.y;
    const float2* q1 = (const float2*)(vp + 6);
    float2 a1q = q1[0], b1q = q1[1], d1q = q1[2];
    vb0 = a1q.x; vb1 = a1q.y; vb2 = b1q.x; vb3 = b1q.y; vb4 = d1q.x; vb5 = d1q.y;
  }
  float viA = vp[i_], vjA = vp[j_];
  float viB = vp[6 + i_], vjB = vp[6 + j_];

#pragma unroll 2
  for (int r = 0; r < CL; ++r) {
    int rn = r + 2; rn = (rn > CL - 1) ? (CL - 1) : rn;
    const float2* qp = (const float2*)(vp + rn * 6);
    const float2 pa = qp[0], pb = qp[1], pd = qp[2];
    const float viC = vp[rn * 6 + i_];
    const float vjC = vp[rn * 6 + j_];

    const float v0 = va0, v1 = va1, v2 = va2;
    const float v3 = va3, v4 = va4, v5 = va5;
    const float vi = viA, vj = vjA;

    const float aa = vi * vj;
    const float sv = s1i * vj;
    const float G2  = fmaf(aa, 1.f / 6.f,  fmaf(sv, 0.5f,      s2));
    const float in4 = fmaf(aa, 1.f / 24.f, fmaf(sv, 1.f / 6.f, s2 * 0.5f));
#define MKG(k)                                    \
    const float G_##k = fmaf(in4, v##k, s3_##k);  \
    s3_##k = fmaf(G2, v##k, s3_##k);
    REP6(MKG)
#undef MKG
#define UPD4(k, l) s4_##k##_##l = fmaf(G_##k, v##l, s4_##k##_##l);
    REP36(UPD4)
#undef UPD4
    s2 = fmaf(fmaf(vi, 0.5f, s1i), vj, s2);
    s1i += vi;

    va0 = vb0; va1 = vb1; va2 = vb2; va3 = vb3; va4 = vb4; va5 = vb5;
    vb0 = pa.x; vb1 = pa.y; vb2 = pb.x; vb3 = pb.y; vb4 = pd.x; vb5 = pd.y;
    viA = viB; vjA = vjB; viB = viC; vjB = vjC;
  }

  // ---- write wave state into LDS (internal layout, stride SSTRIDE) ----
  {
    float* st = Sb + w * SSTRIDE;
    if (lane < 36) {
      float4* o4 = (float4*)(st + OFF4 + pc * 36);
      float4 wv;
      wv.x = s4_0_0; wv.y = s4_0_1; wv.z = s4_0_2; wv.w = s4_0_3; o4[0] = wv;
      wv.x = s4_0_4; wv.y = s4_0_5; wv.z = s4_1_0; wv.w = s4_1_1; o4[1] = wv;
      wv.x = s4_1_2; wv.y = s4_1_3; wv.z = s4_1_4; wv.w = s4_1_5; o4[2] = wv;
      wv.x = s4_2_0; wv.y = s4_2_1; wv.z = s4_2_2; wv.w = s4_2_3; o4[3] = wv;
      wv.x = s4_2_4; wv.y = s4_2_5; wv.z = s4_3_0; wv.w = s4_3_1; o4[4] = wv;
      wv.x = s4_3_2; wv.y = s4_3_3; wv.z = s4_3_4; wv.w = s4_3_5; o4[5] = wv;
      wv.x = s4_4_0; wv.y = s4_4_1; wv.z = s4_4_2; wv.w = s4_4_3; o4[6] = wv;
      wv.x = s4_4_4; wv.y = s4_4_5; wv.z = s4_5_0; wv.w = s4_5_1; o4[7] = wv;
      wv.x = s4_5_2; wv.y = s4_5_3; wv.z = s4_5_4; wv.w = s4_5_5; o4[8] = wv;
#define ST3(k) st[OFF3 + pc * 6 + k] = s3_##k;
      REP6(ST3)
#undef ST3
      st[OFF2 + pc] = s2;
      if (j_ == 0) st[OFF1 + i_] = s1i;
    }
  }
  __syncthreads();

  // ---- Phase B: 216-lane intra-block combine of the 4 wave states ----
  const int tc = (tid < 216) ? tid : 215;
  const bool act2 = (tid < 216);
  const int k2 = tc % 6;
  const int ij2 = tc / 6;
  const int j2 = ij2 % 6;
  const int i2 = ij2 / 6;
  const int oB4 = OFF4 + tc * 6;
  const int oB3r = OFF3 + (j2 * 6 + k2) * 6;
  const int oB2r = OFF2 + k2 * 6;
  const int oB2ij = OFF2 + ij2;
  const int oB2jk = OFF2 + j2 * 6 + k2;
  const int oB3ijk = OFF3 + tc;
  const int oB1k = OFF1 + k2;
  const int oB1j = OFF1 + j2;
  const int oB1i = OFF1 + i2;

  float a4_0, a4_1, a4_2, a4_3, a4_4, a4_5, a3, a2;
  float a1_0, a1_1, a1_2, a1_3, a1_4, a1_5, a1i;
  DECLSET(A)
  DECLSET(B)

  {
    const float* s0 = Sb;
    INITA(s0)
    LOADSET(A, Sb + 1 * SSTRIDE) PROD(A)
    LOADSET(A, Sb + 2 * SSTRIDE) PROD(A)
    LOADSET(A, Sb + 3 * SSTRIDE) PROD(A)
  }

  // block state -> global
  {
    float* dst = ws1 + (size_t)b * PSTRIDE;
    STORE_STATE(dst)
  }
  __threadfence();
  __syncthreads();

  // ---- Phase C1: group election (32 blocks per group) ----
  const int g = b / GSZ;
  const int gbase = g * GSZ;
  int gcnt = NB - gbase; if (gcnt > GSZ) gcnt = GSZ;
  if (tid == 0) {
    int ret = atomicAdd(&ctr[g], 1);
    flag = (ret == gcnt - 1) ? 1 : 0;
  }
  __syncthreads();
  if (!flag) return;
  __threadfence();

  {
    const float* base = ws1 + (size_t)gbase * PSTRIDE;
    INITA(base)
    GLOOP(base, gcnt)
    float* dst = ws2 + (size_t)g * PSTRIDE;
    STORE_STATE(dst)
  }
  __threadfence();
  __syncthreads();

  // ---- Phase C2: final election over NG1 groups ----
  if (tid == 0) {
    int ret = atomicAdd(&ctr[NG1], 1);
    flag = (ret == NG1 - 1) ? 1 : 0;
  }
  __syncthreads();
  if (!flag) return;
  __threadfence();

  {
    const float* base = ws2;
    INITA(base)
    GLOOP(base, NG1)
    // reference layout out: L1[0,6) L2[6,42) L3[42,258) L4[258,1554)
    if (act2) {
      float2* o2 = (float2*)(out + 258 + tc * 6);
      float2 wv;
      wv.x = a4_0; wv.y = a4_1; o2[0] = wv;
      wv.x = a4_2; wv.y = a4_3; o2[1] = wv;
      wv.x = a4_4; wv.y = a4_5; o2[2] = wv;
      out[42 + tc] = a3;
      if (k2 == 0) out[6 + ij2] = a2;
    }
    if (tid < 6) out[tid] = sel6(tid, a1_0, a1_1, a1_2, a1_3, a1_4, a1_5);
  }
}

extern "C" void kernel_launch(void* const* d_in, const int* in_sizes, int n_in,
                              void* d_out, int out_size, void* d_ws, size_t ws_size,
                              hipStream_t stream) {
  const float* x = (const float*)d_in[0];
  const int Lrows = in_sizes[0] / 6;
  const int n_inc = Lrows - 1;

  int CL = (n_inc + 4096 - 1) / 4096;          // target ~1024 blocks
  if (CL < 1) CL = 1;
  if (CL > MAXCL) CL = MAXCL;
  int NB = (n_inc + 4 * CL - 1) / (4 * CL);
  if (NB > NBMAX) NB = NBMAX;                  // (L fixed at 1e5: never hit)
  const int NG1 = (NB + GSZ - 1) / GSZ;        // <= 64

  float* ws1 = (float*)d_ws;
  float* ws2 = ws1 + (size_t)NBMAX * PSTRIDE;
  int* ctr = (int*)(ws2 + (size_t)NGMAX * PSTRIDE);

  hipMemsetAsync(ctr, 0, (size_t)(NG1 + 1) * sizeof(int), stream);
  sig_fused<<<NB, 256, 0, stream>>>(x, ws1, ws2, ctr, (float*)d_out,
                                    n_inc, CL, NB, NG1);
}

// Round 8
// 231.820 us; speedup vs baseline: 1.0098x; 1.0098x over previous
//
#include <hip/hip_runtime.h>

// Depth-4 path signature, D=6 — SINGLE fused launch.
// Phase A: blocks x 256 threads; wave w computes chunk 4b+w via the 36-lane
//   Chen recursion on LDS-precomputed increment rows (zero-padded: v=0 is an
//   exact no-op step, so the loop is branch-free with fixed CL).
// Phase B: block combines its 4 wave-states in LDS (216-lane layout).
// Phase C: last-arriver election (threadfence+atomicAdd):
//   group of 32 blocks -> 31 products; then last of the group-combiners ->
//   31 products -> d_out. Zero states are exact Chen identities.
// All per-lane state is NAMED SCALARS (R2-R4: arrays land in scratch).
//
// NOTE __launch_bounds__(256, 1) is load-bearing: R7 used plain (256) and the
// backend capped VGPRs at 60 -> all named scalars spilled to scratch ->
// 200us dispatch at VALUBusy 4.4%. The ",1" grants the full 512-VGPR budget.
//
// Internal state layout (floats): L4 [0,1296) L3 [1296,1512) L2 [1512,1548)
// L1 [1548,1554). Output uses reference layout L1|L2|L3|L4.
#define SIGSZ 1554
#define PSTRIDE 1600
#define OFF4 0
#define OFF3 1296
#define OFF2 1512
#define OFF1 1548
#define SSTRIDE 1560      // LDS state stride
#define MAXCL 32
#define NBMAX 2048
#define NGMAX 64
#define GSZ 32

#define REP6(M) M(0) M(1) M(2) M(3) M(4) M(5)
#define REP6B(M, k) M(k, 0) M(k, 1) M(k, 2) M(k, 3) M(k, 4) M(k, 5)
#define REP36(M) \
  REP6B(M, 0) REP6B(M, 1) REP6B(M, 2) REP6B(M, 3) REP6B(M, 4) REP6B(M, 5)

__device__ __forceinline__ float sel6(int idx, float a0, float a1, float a2,
                                      float a3, float a4, float a5) {
  float r = a0;
  r = (idx == 1) ? a1 : r;
  r = (idx == 2) ? a2 : r;
  r = (idx == 3) ? a3 : r;
  r = (idx == 4) ? a4 : r;
  r = (idx == 5) ? a5 : r;
  return r;
}

// ---- combine working set: 32 named scalars per prefetch slot ----
#define DECLSET(S)                                                  \
  float S##b4_0, S##b4_1, S##b4_2, S##b4_3, S##b4_4, S##b4_5;       \
  float S##b3r_0, S##b3r_1, S##b3r_2, S##b3r_3, S##b3r_4, S##b3r_5; \
  float S##b2r_0, S##b2r_1, S##b2r_2, S##b2r_3, S##b2r_4, S##b2r_5; \
  float S##b1_0, S##b1_1, S##b1_2, S##b1_3, S##b1_4, S##b1_5;       \
  float S##b2ij, S##b2jk, S##b3ijk, S##b1k, S##b1j, S##b1i;

#define LOADSET(S, bp) {                                            \
  const float2* q4 = (const float2*)((bp) + oB4);                   \
  float2 u0 = q4[0], u1 = q4[1], u2 = q4[2];                        \
  S##b4_0 = u0.x; S##b4_1 = u0.y; S##b4_2 = u1.x;                   \
  S##b4_3 = u1.y; S##b4_4 = u2.x; S##b4_5 = u2.y;                   \
  const float2* q3 = (const float2*)((bp) + oB3r);                  \
  float2 w0 = q3[0], w1 = q3[1], w2 = q3[2];                        \
  S##b3r_0 = w0.x; S##b3r_1 = w0.y; S##b3r_2 = w1.x;                \
  S##b3r_3 = w1.y; S##b3r_4 = w2.x; S##b3r_5 = w2.y;                \
  const float2* q2 = (const float2*)((bp) + oB2r);                  \
  float2 y0 = q2[0], y1 = q2[1], y2 = q2[2];                        \
  S##b2r_0 = y0.x; S##b2r_1 = y0.y; S##b2r_2 = y1.x;                \
  S##b2r_3 = y1.y; S##b2r_4 = y2.x; S##b2r_5 = y2.y;                \
  const float2* q1 = (const float2*)((bp) + OFF1);                  \
  float2 z0 = q1[0], z1 = q1[1], z2 = q1[2];                        \
  S##b1_0 = z0.x; S##b1_1 = z0.y; S##b1_2 = z1.x;                   \
  S##b1_3 = z1.y; S##b1_4 = z2.x; S##b1_5 = z2.y;                   \
  S##b2ij = (bp)[oB2ij]; S##b2jk = (bp)[oB2jk];                     \
  S##b3ijk = (bp)[oB3ijk];                                          \
  S##b1k = (bp)[oB1k]; S##b1j = (bp)[oB1j]; S##b1i = (bp)[oB1i];    \
}

// C = A (x) B, old-A on RHS; updates a-regs in place.
#define PROD(S) {                                                   \
  a4_0 = fmaf(a3, S##b1_0, fmaf(a2, S##b2r_0,                       \
         fmaf(a1i, S##b3r_0, a4_0 + S##b4_0)));                     \
  a4_1 = fmaf(a3, S##b1_1, fmaf(a2, S##b2r_1,                       \
         fmaf(a1i, S##b3r_1, a4_1 + S##b4_1)));                     \
  a4_2 = fmaf(a3, S##b1_2, fmaf(a2, S##b2r_2,                       \
         fmaf(a1i, S##b3r_2, a4_2 + S##b4_2)));                     \
  a4_3 = fmaf(a3, S##b1_3, fmaf(a2, S##b2r_3,                       \
         fmaf(a1i, S##b3r_3, a4_3 + S##b4_3)));                     \
  a4_4 = fmaf(a3, S##b1_4, fmaf(a2, S##b2r_4,                       \
         fmaf(a1i, S##b3r_4, a4_4 + S##b4_4)));                     \
  a4_5 = fmaf(a3, S##b1_5, fmaf(a2, S##b2r_5,                       \
         fmaf(a1i, S##b3r_5, a4_5 + S##b4_5)));                     \
  a3 = fmaf(a2, S##b1k, fmaf(a1i, S##b2jk, a3 + S##b3ijk));         \
  a2 = fmaf(a1i, S##b1j, a2 + S##b2ij);                             \
  a1i += S##b1i;                                                    \
  a1_0 += S##b1_0; a1_1 += S##b1_1; a1_2 += S##b1_2;                \
  a1_3 += S##b1_3; a1_4 += S##b1_4; a1_5 += S##b1_5;                \
}

#define INITA(bp) {                                                 \
  const float2* q4 = (const float2*)((bp) + oB4);                   \
  float2 u0 = q4[0], u1 = q4[1], u2 = q4[2];                        \
  a4_0 = u0.x; a4_1 = u0.y; a4_2 = u1.x;                            \
  a4_3 = u1.y; a4_4 = u2.x; a4_5 = u2.y;                            \
  a3 = (bp)[oB3ijk]; a2 = (bp)[oB2ij];                              \
  const float2* q1 = (const float2*)((bp) + OFF1);                  \
  float2 z0 = q1[0], z1 = q1[1], z2 = q1[2];                        \
  a1_0 = z0.x; a1_1 = z0.y; a1_2 = z1.x;                            \
  a1_3 = z1.y; a1_4 = z2.x; a1_5 = z2.y;                            \
  a1i = (bp)[oB1i];                                                 \
}

// left-to-right combine of states base[1..n-1] into a-regs (A=base[0] loaded
// by INITA), 2-deep ping-pong prefetch, clamped tail loads.
#define GCLAMP(sx, n) (((sx) < (n)) ? (sx) : ((n) - 1))
#define GLOOP(base, n) {                                            \
  int s_ = 1;                                                       \
  LOADSET(A, (base) + (size_t)GCLAMP(1, (n)) * PSTRIDE)             \
  LOADSET(B, (base) + (size_t)GCLAMP(2, (n)) * PSTRIDE)             \
  while (s_ + 1 < (n)) {                                            \
    PROD(A)                                                         \
    LOADSET(A, (base) + (size_t)GCLAMP(s_ + 2, (n)) * PSTRIDE)      \
    PROD(B)                                                         \
    LOADSET(B, (base) + (size_t)GCLAMP(s_ + 3, (n)) * PSTRIDE)      \
    s_ += 2;                                                        \
  }                                                                 \
  if (s_ < (n)) { PROD(A) }                                         \
}

// write a-regs as an internal-layout state (216-lane)
#define STORE_STATE(dst) {                                          \
  if (act2) {                                                       \
    float2* o2 = (float2*)((dst) + oB4);                            \
    float2 wv_;                                                     \
    wv_.x = a4_0; wv_.y = a4_1; o2[0] = wv_;                        \
    wv_.x = a4_2; wv_.y = a4_3; o2[1] = wv_;                        \
    wv_.x = a4_4; wv_.y = a4_5; o2[2] = wv_;                        \
    (dst)[oB3ijk] = a3;                                             \
    if (k2 == 0) (dst)[oB2ij] = a2;                                 \
  }                                                                 \
  if (tid < 6) (dst)[OFF1 + tid] = sel6(tid, a1_0, a1_1, a1_2,      \
                                        a1_3, a1_4, a1_5);          \
}

__global__ __launch_bounds__(256, 1) void sig_fused(
    const float* __restrict__ x, float* __restrict__ ws1,
    float* __restrict__ ws2, int* __restrict__ ctr,
    float* __restrict__ out, int n_inc, int CL, int NB, int NG1) {
  __shared__ __align__(16) float xls[(4 * MAXCL + 1) * 6];
  __shared__ __align__(16) float vls[4 * MAXCL * 6];
  __shared__ __align__(16) float Sb[4 * SSTRIDE];
  __shared__ int flag;

  const int b = blockIdx.x;
  const int tid = threadIdx.x;
  const int w = tid >> 6;
  const int lane = tid & 63;

  // ---- stage x rows, then zero-padded increment rows, into LDS ----
  const int t0b = b * 4 * CL;
  const int xtot = (4 * CL + 1) * 6;
  const int xlim = (n_inc + 1) * 6 - t0b * 6;   // valid staged floats
  for (int idx = tid; idx < xtot; idx += 256)
    xls[idx] = (idx < xlim) ? x[(size_t)t0b * 6 + idx] : 0.f;
  __syncthreads();
  const int remi = n_inc - t0b;
  const int vlim = (remi > 0) ? remi * 6 : 0;
  const int vtot = 4 * CL * 6;
  for (int idx = tid; idx < vtot; idx += 256)
    vls[idx] = (idx < vlim) ? (xls[idx + 6] - xls[idx]) : 0.f;
  __syncthreads();

  // ---- Phase A: per-wave 36-lane Chen recursion over CL increments ----
  const int pc = (lane < 36) ? lane : 35;
  const int i_ = pc / 6, j_ = pc % 6;

#define DECL_S4(k, l) float s4_##k##_##l = 0.f;
  REP36(DECL_S4)
#undef DECL_S4
#define DECL_S3(k) float s3_##k = 0.f;
  REP6(DECL_S3)
#undef DECL_S3
  float s1i = 0.f, s2 = 0.f;

  const float* vp = vls + w * CL * 6;
  float va0, va1, va2, va3, va4, va5, vb0, vb1, vb2, vb3, vb4, vb5;
  {
    const float2* q0 = (const float2*)(vp);
    float2 a0 = q0[0], b0 = q0[1], d0 = q0[2];
    va0 = a0.x; va1 = a0.y; va2 = b0.x; va3 = b0.y; va4 = d0.x; va5 = d0.y;
    const float2* q1 = (const float2*)(vp + 6);
    float2 a1q = q1[0], b1q = q1[1], d1q = q1[2];
    vb0 = a1q.x; vb1 = a1q.y; vb2 = b1q.x; vb3 = b1q.y; vb4 = d1q.x; vb5 = d1q.y;
  }
  float viA = vp[i_], vjA = vp[j_];
  float viB = vp[6 + i_], vjB = vp[6 + j_];

#pragma unroll 2
  for (int r = 0; r < CL; ++r) {
    int rn = r + 2; rn = (rn > CL - 1) ? (CL - 1) : rn;
    const float2* qp = (const float2*)(vp + rn * 6);
    const float2 pa = qp[0], pb = qp[1], pd = qp[2];
    const float viC = vp[rn * 6 + i_];
    const float vjC = vp[rn * 6 + j_];

    const float v0 = va0, v1 = va1, v2 = va2;
    const float v3 = va3, v4 = va4, v5 = va5;
    const float vi = viA, vj = vjA;

    const float aa = vi * vj;
    const float sv = s1i * vj;
    const float G2  = fmaf(aa, 1.f / 6.f,  fmaf(sv, 0.5f,      s2));
    const float in4 = fmaf(aa, 1.f / 24.f, fmaf(sv, 1.f / 6.f, s2 * 0.5f));
#define MKG(k)                                    \
    const float G_##k = fmaf(in4, v##k, s3_##k);  \
    s3_##k = fmaf(G2, v##k, s3_##k);
    REP6(MKG)
#undef MKG
#define UPD4(k, l) s4_##k##_##l = fmaf(G_##k, v##l, s4_##k##_##l);
    REP36(UPD4)
#undef UPD4
    s2 = fmaf(fmaf(vi, 0.5f, s1i), vj, s2);
    s1i += vi;

    va0 = vb0; va1 = vb1; va2 = vb2; va3 = vb3; va4 = vb4; va5 = vb5;
    vb0 = pa.x; vb1 = pa.y; vb2 = pb.x; vb3 = pb.y; vb4 = pd.x; vb5 = pd.y;
    viA = viB; vjA = vjB; viB = viC; vjB = vjC;
  }

  // ---- write wave state into LDS (internal layout, stride SSTRIDE) ----
  {
    float* st = Sb + w * SSTRIDE;
    if (lane < 36) {
      float4* o4 = (float4*)(st + OFF4 + pc * 36);
      float4 wv;
      wv.x = s4_0_0; wv.y = s4_0_1; wv.z = s4_0_2; wv.w = s4_0_3; o4[0] = wv;
      wv.x = s4_0_4; wv.y = s4_0_5; wv.z = s4_1_0; wv.w = s4_1_1; o4[1] = wv;
      wv.x = s4_1_2; wv.y = s4_1_3; wv.z = s4_1_4; wv.w = s4_1_5; o4[2] = wv;
      wv.x = s4_2_0; wv.y = s4_2_1; wv.z = s4_2_2; wv.w = s4_2_3; o4[3] = wv;
      wv.x = s4_2_4; wv.y = s4_2_5; wv.z = s4_3_0; wv.w = s4_3_1; o4[4] = wv;
      wv.x = s4_3_2; wv.y = s4_3_3; wv.z = s4_3_4; wv.w = s4_3_5; o4[5] = wv;
      wv.x = s4_4_0; wv.y = s4_4_1; wv.z = s4_4_2; wv.w = s4_4_3; o4[6] = wv;
      wv.x = s4_4_4; wv.y = s4_4_5; wv.z = s4_5_0; wv.w = s4_5_1; o4[7] = wv;
      wv.x = s4_5_2; wv.y = s4_5_3; wv.z = s4_5_4; wv.w = s4_5_5; o4[8] = wv;
#define ST3(k) st[OFF3 + pc * 6 + k] = s3_##k;
      REP6(ST3)
#undef ST3
      st[OFF2 + pc] = s2;
      if (j_ == 0) st[OFF1 + i_] = s1i;
    }
  }
  __syncthreads();

  // ---- Phase B: 216-lane intra-block combine of the 4 wave states ----
  const int tc = (tid < 216) ? tid : 215;
  const bool act2 = (tid < 216);
  const int k2 = tc % 6;
  const int ij2 = tc / 6;
  const int j2 = ij2 % 6;
  const int i2 = ij2 / 6;
  const int oB4 = OFF4 + tc * 6;
  const int oB3r = OFF3 + (j2 * 6 + k2) * 6;
  const int oB2r = OFF2 + k2 * 6;
  const int oB2ij = OFF2 + ij2;
  const int oB2jk = OFF2 + j2 * 6 + k2;
  const int oB3ijk = OFF3 + tc;
  const int oB1k = OFF1 + k2;
  const int oB1j = OFF1 + j2;
  const int oB1i = OFF1 + i2;

  float a4_0, a4_1, a4_2, a4_3, a4_4, a4_5, a3, a2;
  float a1_0, a1_1, a1_2, a1_3, a1_4, a1_5, a1i;
  DECLSET(A)
  DECLSET(B)

  {
    const float* s0 = Sb;
    INITA(s0)
    LOADSET(A, Sb + 1 * SSTRIDE) PROD(A)
    LOADSET(A, Sb + 2 * SSTRIDE) PROD(A)
    LOADSET(A, Sb + 3 * SSTRIDE) PROD(A)
  }

  // block state -> global
  {
    float* dst = ws1 + (size_t)b * PSTRIDE;
    STORE_STATE(dst)
  }
  __threadfence();
  __syncthreads();

  // ---- Phase C1: group election (32 blocks per group) ----
  const int g = b / GSZ;
  const int gbase = g * GSZ;
  int gcnt = NB - gbase; if (gcnt > GSZ) gcnt = GSZ;
  if (tid == 0) {
    int ret = atomicAdd(&ctr[g], 1);
    flag = (ret == gcnt - 1) ? 1 : 0;
  }
  __syncthreads();
  if (!flag) return;
  __threadfence();

  {
    const float* base = ws1 + (size_t)gbase * PSTRIDE;
    INITA(base)
    GLOOP(base, gcnt)
    float* dst = ws2 + (size_t)g * PSTRIDE;
    STORE_STATE(dst)
  }
  __threadfence();
  __syncthreads();

  // ---- Phase C2: final election over NG1 groups ----
  if (tid == 0) {
    int ret = atomicAdd(&ctr[NG1], 1);
    flag = (ret == NG1 - 1) ? 1 : 0;
  }
  __syncthreads();
  if (!flag) return;
  __threadfence();

  {
    const float* base = ws2;
    INITA(base)
    GLOOP(base, NG1)
    // reference layout out: L1[0,6) L2[6,42) L3[42,258) L4[258,1554)
    if (act2) {
      float2* o2 = (float2*)(out + 258 + tc * 6);
      float2 wv;
      wv.x = a4_0; wv.y = a4_1; o2[0] = wv;
      wv.x = a4_2; wv.y = a4_3; o2[1] = wv;
      wv.x = a4_4; wv.y = a4_5; o2[2] = wv;
      out[42 + tc] = a3;
      if (k2 == 0) out[6 + ij2] = a2;
    }
    if (tid < 6) out[tid] = sel6(tid, a1_0, a1_1, a1_2, a1_3, a1_4, a1_5);
  }
}

extern "C" void kernel_launch(void* const* d_in, const int* in_sizes, int n_in,
                              void* d_out, int out_size, void* d_ws, size_t ws_size,
                              hipStream_t stream) {
  const float* x = (const float*)d_in[0];
  const int Lrows = in_sizes[0] / 6;
  const int n_inc = Lrows - 1;

  int CL = (n_inc + 4096 - 1) / 4096;          // target ~1024 blocks
  if (CL < 1) CL = 1;
  if (CL > MAXCL) CL = MAXCL;
  int NB = (n_inc + 4 * CL - 1) / (4 * CL);
  if (NB > NBMAX) NB = NBMAX;                  // (L fixed at 1e5: never hit)
  const int NG1 = (NB + GSZ - 1) / GSZ;        // <= 64

  float* ws1 = (float*)d_ws;
  float* ws2 = ws1 + (size_t)NBMAX * PSTRIDE;
  int* ctr = (int*)(ws2 + (size_t)NGMAX * PSTRIDE);

  hipMemsetAsync(ctr, 0, (size_t)(NG1 + 1) * sizeof(int), stream);
  sig_fused<<<NB, 256, 0, stream>>>(x, ws1, ws2, ctr, (float*)d_out,
                                    n_inc, CL, NB, NG1);
}